// Round 5
// baseline (1435.913 us; speedup 1.0000x reference)
//
#include <hip/hip_runtime.h>

typedef __attribute__((ext_vector_type(4))) float f32x4_t;
typedef __attribute__((ext_vector_type(8))) short bf16x8_t;

#define NROWS 16384
#define NCODES 4096
#define DIM 512
#define LSTR 65
#define DELTA 0.005f     // > worst-case |f64 referee - hi*hi pass1| = 0.0040

// ---------------- workspace byte offsets (~30.3 MB; harness gives >=45.6 MB) ----------------
#define WS_A      0u          // 128 tb x 8 stages x 16KB bf16-hi chunks  -> 16777216
#define WS_B      16777216u   //  32 ct x 8 stages x 16KB                 -> 20971520
#define WS_TOP8   20971520u   // 16384 x 8 grp x 8 slot x float2          -> 29360128
#define WS_COUNTS 29360128u   // 4096 u32                                 -> 29376512
#define WS_FLAGS  29376512u   // [0]=mask-layout [1]=cand_cnt [2]=full_cnt -> (+64)
#define WS_IDX    29376576u   // 16384 i32                                -> 29442112
#define WS_CANDS  29442112u   // 16384 x 12 i32 (row,cnt,idx[8],pad)      -> 30228544
#define WS_FULL   30228544u   // 16384 i32                                -> 30294080
#define WS_CPART  30294080u   // 4096 f64                                 -> 30326848

// output element offsets (flat f32)
#define OUT_ZQ      0
#define OUT_ZQST    8388608
#define OUT_IDX     16777216
#define OUT_VQ      16793600
#define OUT_COMMIT  16793601
#define OUT_PERP    16793602

__device__ __forceinline__ unsigned short f2bf(float x) {
  unsigned u = __builtin_bit_cast(unsigned, x);
  unsigned r = (u + 0x7FFFu + ((u >> 16) & 1u)) >> 16;  // RNE
  return (unsigned short)r;
}
__device__ __forceinline__ unsigned hz(unsigned x) {
  return (x - 0x01010101u) & ~x & 0x80808080u;  // any zero byte
}

// ---------------- prep: norms + bf16-hi convert into swizzled chunks + zero counts/flags ----------------
// one wave per row; lane l handles cols [l*8, l*8+8) -> stage st=l>>3, unit u=l&7
// chunk(tb,st): byte off = r*128 + ((u ^ (r&7))<<4)  (XOR keeps ds_read banks uniform)
__global__ void prep_kernel(const float* __restrict__ z, const float* __restrict__ cb,
                            unsigned char* __restrict__ Aws, unsigned char* __restrict__ Bws,
                            unsigned* __restrict__ counts) {
  if (blockIdx.x < 17) {
    int zi = blockIdx.x * 256 + threadIdx.x;
    if (zi < 4100) counts[zi] = 0;  // counts[4096] + flags[4] contiguous
  }
  const int wv = threadIdx.x >> 6, lane = threadIdx.x & 63;
  const int row = blockIdx.x * 4 + wv;
  if (row >= NROWS + NCODES) return;
  const bool isA = row < NROWS;
  const int lrow = isA ? row : row - NROWS;
  const float* src = (isA ? z : cb) + (size_t)lrow * DIM;
  f32x4_t a = *(const f32x4_t*)(src + lane * 8);
  f32x4_t b = *(const f32x4_t*)(src + lane * 8 + 4);
  double s = 0.0;
#pragma unroll
  for (int e = 0; e < 4; ++e) s += (double)a[e] * a[e] + (double)b[e] * b[e];
#pragma unroll
  for (int off = 1; off < 64; off <<= 1) s += __shfl_xor(s, off);
  const float inv = (float)(1.0 / fmax(sqrt(s), 1e-8));
  union { unsigned short u[8]; uint4 v; } H;
#pragma unroll
  for (int e = 0; e < 4; ++e) {
    H.u[e] = f2bf(a[e] * inv);
    H.u[4 + e] = f2bf(b[e] * inv);
  }
  const int tb = lrow >> 7, r = lrow & 127;
  const int st = lane >> 3, u = lane & 7;
  unsigned char* chunk = (isA ? Aws : Bws) + ((size_t)tb * 8 + st) * 16384;
  *(uint4*)(chunk + r * 128 + ((u ^ (r & 7)) << 4)) = H.v;
}

// ---------------- pass-1 GEMM (hi*hi only) + per-(row,group) top-8 ----------------
// XCD-aware: all 8 col-group blocks of one row-block land on one XCD -> A L2-resident.
__global__ __launch_bounds__(256, 2) void gemm_p1_kernel(
    const unsigned char* __restrict__ Aws, const unsigned char* __restrict__ Bws,
    float2* __restrict__ top8) {
  __shared__ unsigned char lds[65536];  // dbuf 2 x (A 16KB | B 16KB); slog unions buf space
  float* slog = (float*)lds;

  const int tid = threadIdx.x;
  const int bid = blockIdx.x;
  const int xcd = bid & 7, q = bid >> 3;
  const int rb = xcd * 16 + (q >> 3), cg = q & 7;
  const int wave = tid >> 6, lane = tid & 63;
  const int wr = wave >> 1, wc = wave & 1;
  const int kg = lane >> 4, lr = lane & 15;

  float v8[8]; int id8[8];
#pragma unroll
  for (int s = 0; s < 8; ++s) { v8[s] = -3e38f; id8[s] = 0; }

  const unsigned char* Ach = Aws + (size_t)rb * 8 * 16384;

  for (int ct = 0; ct < 4; ++ct) {
    const int ctile = cg * 4 + ct;
    const int code0 = ctile * 128;
    const unsigned char* Bch = Bws + (size_t)ctile * 8 * 16384;

    f32x4_t acc[4][4];
#pragma unroll
    for (int m = 0; m < 4; ++m)
#pragma unroll
      for (int n = 0; n < 4; ++n) acc[m][n] = (f32x4_t){0.f, 0.f, 0.f, 0.f};

    // prologue: stage 0 -> buf0 (32 x 1KB calls, 8 per wave)
#pragma unroll
    for (int i = 0; i < 8; ++i) {
      const int j = wave * 8 + i;
      const unsigned char* sp = (j < 16) ? (Ach + (size_t)j * 1024 + lane * 16)
                                         : (Bch + (size_t)(j - 16) * 1024 + lane * 16);
      __builtin_amdgcn_global_load_lds(
          (const __attribute__((address_space(1))) void*)sp,
          (__attribute__((address_space(3))) void*)(lds + j * 1024), 16, 0, 0);
    }

    for (int st = 0; st < 8; ++st) {
      const int cur = st & 1;
      if (st < 7) {
        unsigned char* dbase = lds + (cur ^ 1) * 32768;
        const unsigned char* An = Ach + (size_t)(st + 1) * 16384;
        const unsigned char* Bn = Bch + (size_t)(st + 1) * 16384;
#pragma unroll
        for (int i = 0; i < 8; ++i) {
          const int j = wave * 8 + i;
          const unsigned char* sp = (j < 16) ? (An + (size_t)j * 1024 + lane * 16)
                                             : (Bn + (size_t)(j - 16) * 1024 + lane * 16);
          __builtin_amdgcn_global_load_lds(
              (const __attribute__((address_space(1))) void*)sp,
              (__attribute__((address_space(3))) void*)(dbase + j * 1024), 16, 0, 0);
        }
        asm volatile("s_waitcnt vmcnt(8)" ::: "memory");  // cur's 8 done; next 8 in flight
      } else {
        asm volatile("s_waitcnt vmcnt(0)" ::: "memory");
      }
      __builtin_amdgcn_s_barrier();

      const unsigned char* base = lds + cur * 32768;
      bf16x8_t ah[2][4], bh[2][4];
#pragma unroll
      for (int k2 = 0; k2 < 2; ++k2) {
        const int u = k2 * 4 + kg;
#pragma unroll
        for (int m = 0; m < 4; ++m) {
          const int r = wr * 64 + m * 16 + lr;
          ah[k2][m] = *(const bf16x8_t*)(base + r * 128 + ((u ^ (r & 7)) << 4));
        }
#pragma unroll
        for (int n = 0; n < 4; ++n) {
          const int r = wc * 64 + n * 16 + lr;
          bh[k2][n] = *(const bf16x8_t*)(base + 16384 + r * 128 + ((u ^ (r & 7)) << 4));
        }
      }
#pragma unroll
      for (int k2 = 0; k2 < 2; ++k2)
#pragma unroll
        for (int m = 0; m < 4; ++m)
#pragma unroll
          for (int n = 0; n < 4; ++n)
            acc[m][n] = __builtin_amdgcn_mfma_f32_16x16x32_bf16(ah[k2][m], bh[k2][n], acc[m][n], 0, 0, 0);
      asm volatile("s_waitcnt lgkmcnt(0)" ::: "memory");
      __builtin_amdgcn_s_barrier();  // cur buffer free for overwrite
    }
    __syncthreads();

    // epilogue: 64-col halves through LDS, per-row top-8 insertion
#pragma unroll
    for (int ph = 0; ph < 2; ++ph) {
      if (wc == ph) {
#pragma unroll
        for (int m = 0; m < 4; ++m)
#pragma unroll
          for (int n = 0; n < 4; ++n)
#pragma unroll
            for (int j = 0; j < 4; ++j)
              slog[(wr * 64 + m * 16 + kg * 4 + j) * LSTR + n * 16 + lr] = acc[m][n][j];
      }
      __syncthreads();
      if (tid < 128) {
        const int gbase = code0 + ph * 64;
        for (int c = 0; c < 64; ++c) {
          float v = slog[tid * LSTR + c];
          if (v > v8[7]) {
            v8[7] = v; id8[7] = gbase + c;
#pragma unroll
            for (int s = 7; s > 0; --s)
              if (v8[s] > v8[s - 1]) {
                float tv = v8[s]; v8[s] = v8[s - 1]; v8[s - 1] = tv;
                int ti = id8[s]; id8[s] = id8[s - 1]; id8[s - 1] = ti;
              }
          }
        }
      }
      __syncthreads();
    }
  }

  if (tid < 128) {
    float2* p = top8 + ((size_t)(rb * 128 + tid) * 8 + cg) * 8;
#pragma unroll
    for (int s = 0; s < 8; ++s)
      p[s] = make_float2(v8[s], __builtin_bit_cast(float, id8[s]));
  }
}

// ---------------- resolve: mask probe + merge 8x top-8, classify rows ----------------
__global__ void resolve_kernel(const uint4* __restrict__ mk, const float2* __restrict__ top8,
                               int* __restrict__ idxf, int* __restrict__ cands,
                               int* __restrict__ full, unsigned* __restrict__ flags) {
  if (blockIdx.x == 0) {
    unsigned f = 0;
    for (int i = threadIdx.x; i < 1024; i += 256) {
      uint4 v = mk[i];
      f |= hz(v.x) | hz(v.y) | hz(v.z) | hz(v.w);
    }
    if (f) atomicOr(&flags[0], 1u);  // zero byte found -> int32 mask layout
  }
  const int row = blockIdx.x * 256 + threadIdx.x;
  if (row >= NROWS) return;
  const float2* e = top8 + (size_t)row * 64;
  float V1 = -3e38f; int I1 = 0;
  for (int j = 0; j < 64; ++j) {
    float v = e[j].x;
    if (v > V1) { V1 = v; I1 = __builtin_bit_cast(int, e[j].y); }
  }
  const float T = V1 - 2.0f * DELTA;
  bool fullscan = false;
#pragma unroll
  for (int g = 0; g < 8; ++g)
    if (e[g * 8 + 7].x >= T) fullscan = true;  // group top-8 may have truncated candidates
  int cnt = 0; int cid[8];
  for (int j = 0; j < 64; ++j) {
    if (e[j].x >= T) { if (cnt < 8) cid[cnt] = __builtin_bit_cast(int, e[j].y); ++cnt; }
  }
  if (cnt > 8) fullscan = true;
  idxf[row] = I1;  // default: pass-1 argmax (provably correct when cnt==1)
  if (fullscan) {
    unsigned s = atomicAdd(&flags[2], 1u);
    if (s < NROWS) full[s] = row;
  } else if (cnt >= 2) {
    unsigned s = atomicAdd(&flags[1], 1u);
    int* o = cands + (size_t)s * 12;
    o[0] = row; o[1] = cnt;
#pragma unroll
    for (int c2 = 0; c2 < 8; ++c2) o[2 + c2] = (c2 < cnt) ? cid[c2] : 0;
  }
}

// ---------------- f64 referee: candidate rescore (blocks 0-127) + full scan (blocks 128-159) ----------------
__global__ void rescore_kernel(const float* __restrict__ z, const float* __restrict__ cb,
                               const int* __restrict__ cands, const int* __restrict__ full,
                               const unsigned* __restrict__ flags, int* __restrict__ idxf) {
  __shared__ float zrow[DIM];
  __shared__ double rv[256];
  __shared__ int ri[256];
  if (blockIdx.x < 128) {
    const int lane = threadIdx.x & 63;
    const int gw = (blockIdx.x * 256 + threadIdx.x) >> 6;
    const unsigned n = flags[1];
    for (unsigned it = gw; it < n; it += 512) {
      const int* en = cands + (size_t)it * 12;
      const int row = en[0], cnt = en[1];
      const float* zr = z + (size_t)row * DIM + lane * 8;
      double zv[8];
#pragma unroll
      for (int j = 0; j < 8; ++j) zv[j] = (double)zr[j];
      double bs = -1e300; int bi = 1 << 30;
      for (int c = 0; c < cnt; ++c) {
        const int k = en[2 + c];
        const float* ck = cb + (size_t)k * DIM + lane * 8;
        double da = 0, nb = 0;
#pragma unroll
        for (int j = 0; j < 8; ++j) { double cv = ck[j]; da += zv[j] * cv; nb += cv * cv; }
#pragma unroll
        for (int off = 1; off < 64; off <<= 1) {
          da += __shfl_xor(da, off); nb += __shfl_xor(nb, off);
        }
        double sc = da / sqrt(nb);  // z-norm omitted: row-constant, argmax-invariant
        if (sc > bs || (sc == bs && k < bi)) { bs = sc; bi = k; }
      }
      if (lane == 0) idxf[row] = bi;
    }
  } else {
    const int t = threadIdx.x;
    const unsigned n = flags[2];
    for (unsigned it = blockIdx.x - 128; it < n; it += 32) {
      const int row = full[it];
      for (int j = t; j < DIM; j += 256) zrow[j] = z[(size_t)row * DIM + j];
      __syncthreads();
      double bv = -1e300; int bi = 1 << 30;
      for (int k = t; k < NCODES; k += 256) {
        const float* ck = cb + (size_t)k * DIM;
        double d = 0, nn = 0;
        for (int j = 0; j < DIM; ++j) { double c = ck[j]; d += (double)zrow[j] * c; nn += c * c; }
        double s = d / sqrt(nn);
        if (s > bv || (s == bv && k < bi)) { bv = s; bi = k; }
      }
      rv[t] = bv; ri[t] = bi; __syncthreads();
      for (int off = 128; off; off >>= 1) {
        if (t < off) {
          if (rv[t + off] > rv[t] || (rv[t + off] == rv[t] && ri[t + off] < ri[t])) {
            rv[t] = rv[t + off]; ri[t] = ri[t + off];
          }
        }
        __syncthreads();
      }
      if (t == 0) idxf[row] = ri[0];
      __syncthreads();
    }
  }
}

// ---------------- gather + straight-through + partial losses ----------------
__global__ void outputs_kernel(const float* __restrict__ z, const float* __restrict__ cb,
                               const unsigned char* __restrict__ mask8, const int* __restrict__ mask32,
                               const unsigned* __restrict__ flags, const int* __restrict__ idxf,
                               float* __restrict__ out, unsigned* __restrict__ counts,
                               double* __restrict__ cpart) {
  __shared__ double wsum[4];
  const int wv = threadIdx.x >> 6, lane = threadIdx.x & 63;
  const int row = blockIdx.x * 4 + wv;
  int idx = idxf[row];
  idx = (idx < 0) ? 0 : ((idx > NCODES - 1) ? NCODES - 1 : idx);  // defensive clamp
  const int mi = flags[0] ? (mask32[row] != 0) : (mask8[row] != 0);
  const float mf = mi ? 1.0f : 0.0f;
  const float* zr = z + (size_t)row * DIM;
  const float* cr = cb + (size_t)idx * DIM;
  double cs = 0.0;
#pragma unroll
  for (int h = 0; h < 2; ++h) {
    const int j = h * 256 + lane * 4;
    f32x4_t c  = *(const f32x4_t*)(cr + j);
    f32x4_t ze = *(const f32x4_t*)(zr + j);
    f32x4_t zq, zs;
#pragma unroll
    for (int e = 0; e < 4; ++e) {
      float qv = c[e] * mf;
      float d = qv - ze[e];
      zq[e] = qv;
      zs[e] = ze[e] + d;
      cs += (double)(d * d) * mf;
    }
    *(f32x4_t*)(out + OUT_ZQ   + (size_t)row * DIM + j) = zq;
    *(f32x4_t*)(out + OUT_ZQST + (size_t)row * DIM + j) = zs;
  }
#pragma unroll
  for (int off = 32; off; off >>= 1) cs += __shfl_down(cs, off);
  if (lane == 0) {
    wsum[wv] = cs;
    out[OUT_IDX + row] = (float)idx;
    if (mi) atomicAdd(&counts[idx], 1u);
  }
  __syncthreads();
  if (threadIdx.x == 0) cpart[blockIdx.x] = wsum[0] + wsum[1] + wsum[2] + wsum[3];
}

// ---------------- scalars ----------------
__global__ void finalize_kernel(const double* __restrict__ cpart, const unsigned* __restrict__ counts,
                                float* __restrict__ out) {
  __shared__ double sd[256];
  const int t = threadIdx.x;
  double s = 0;
  for (int i = t; i < 4096; i += 256) s += cpart[i];
  sd[t] = s; __syncthreads();
  for (int off = 128; off; off >>= 1) { if (t < off) sd[t] += sd[t + off]; __syncthreads(); }
  const double commit_sum = sd[0];
  __syncthreads();
  double c = 0;
  for (int i = t; i < 4096; i += 256) c += (double)counts[i];
  sd[t] = c; __syncthreads();
  for (int off = 128; off; off >>= 1) { if (t < off) sd[t] += sd[t + off]; __syncthreads(); }
  const double totc = sd[0];
  __syncthreads();
  const double denom = totc + 1e-5;
  double ent = 0;
  for (int i = t; i < 4096; i += 256) {
    double p = (double)counts[i] / denom;
    ent -= p * log(p + 1e-5);
  }
  sd[t] = ent; __syncthreads();
  for (int off = 128; off; off >>= 1) { if (t < off) sd[t] += sd[t + off]; __syncthreads(); }
  if (t == 0) {
    const double valid = fmax(totc, 1.0);
    const double commitment = commit_sum / valid;
    out[OUT_VQ]     = (float)(0.25 * commitment);
    out[OUT_COMMIT] = (float)commitment;
    out[OUT_PERP]   = (float)exp(sd[0]);
  }
}

extern "C" void kernel_launch(void* const* d_in, const int* in_sizes, int n_in,
                              void* d_out, int out_size, void* d_ws, size_t ws_size,
                              hipStream_t stream) {
  const float* z  = (const float*)d_in[0];
  const void*  mk = d_in[1];
  const float* cb = (const float*)d_in[2];
  float* out = (float*)d_out;
  char* ws = (char*)d_ws;

  unsigned char* Aws   = (unsigned char*)(ws + WS_A);
  unsigned char* Bws   = (unsigned char*)(ws + WS_B);
  float2*        top8  = (float2*)(ws + WS_TOP8);
  unsigned*      counts = (unsigned*)(ws + WS_COUNTS);
  unsigned*      flags  = (unsigned*)(ws + WS_FLAGS);
  int*           idxf   = (int*)(ws + WS_IDX);
  int*           cands  = (int*)(ws + WS_CANDS);
  int*           full   = (int*)(ws + WS_FULL);
  double*        cpart  = (double*)(ws + WS_CPART);

  prep_kernel<<<(NROWS + NCODES) / 4, 256, 0, stream>>>(z, cb, Aws, Bws, counts);
  gemm_p1_kernel<<<1024, 256, 0, stream>>>(Aws, Bws, top8);
  resolve_kernel<<<NROWS / 256, 256, 0, stream>>>((const uint4*)mk, top8, idxf, cands, full, flags);
  rescore_kernel<<<160, 256, 0, stream>>>(z, cb, cands, full, flags, idxf);
  outputs_kernel<<<NROWS / 4, 256, 0, stream>>>(z, cb, (const unsigned char*)mk, (const int*)mk,
                                                flags, idxf, out, counts, cpart);
  finalize_kernel<<<1, 256, 0, stream>>>(cpart, counts, out);
}

// Round 6
// 419.408 us; speedup vs baseline: 3.4237x; 3.4237x over previous
//
#include <hip/hip_runtime.h>

typedef __attribute__((ext_vector_type(4))) float f32x4_t;
typedef __attribute__((ext_vector_type(8))) short bf16x8_t;

#define NROWS 16384
#define NCODES 4096
#define DIM 512
#define LSTR 65
#define DELTA 0.005f     // > worst-case |f64 referee - hi*hi pass1| = 0.0040
#define MAXC 16          // candidate cap per row

// ---------------- workspace byte offsets (~30.9 MB; harness provides >=45.6 MB) ----------------
#define WS_A      0u          // 128 tb x 8 stages x 16KB bf16-hi chunks  -> 16777216
#define WS_B      16777216u   //  32 ct x 8 stages x 16KB                 -> 20971520
#define WS_TOP8   20971520u   // 16384 x 8 grp x 8 slot x float2          -> 29360128
#define WS_COUNTS 29360128u   // 4096 u32                                 -> 29376512
#define WS_FLAGS  29376512u   // [0]=mask-layout [1]=cand_cnt [2]=full_cnt -> +64
#define WS_IDX    29376576u   // 16384 i32                                -> 29442112
#define WS_CANDS  29442112u   // 16384 x 20 i32 (row,cnt,idx[16],pad2)    -> 30752832
#define WS_FULL   30752832u   // 16384 i32                                -> 30817472
#define WS_CPART  30817472u   // 4096 f64                                 -> 30850240

// output element offsets (flat f32)
#define OUT_ZQ      0
#define OUT_ZQST    8388608
#define OUT_IDX     16777216
#define OUT_VQ      16793600
#define OUT_COMMIT  16793601
#define OUT_PERP    16793602

__device__ __forceinline__ unsigned short f2bf(float x) {
  unsigned u = __builtin_bit_cast(unsigned, x);
  unsigned r = (u + 0x7FFFu + ((u >> 16) & 1u)) >> 16;  // RNE
  return (unsigned short)r;
}
__device__ __forceinline__ unsigned hz(unsigned x) {
  return (x - 0x01010101u) & ~x & 0x80808080u;  // any zero byte
}

// ---------------- prep: norms + bf16-hi convert into swizzled chunks + zero counts/flags ----------------
__global__ void prep_kernel(const float* __restrict__ z, const float* __restrict__ cb,
                            unsigned char* __restrict__ Aws, unsigned char* __restrict__ Bws,
                            unsigned* __restrict__ counts) {
  if (blockIdx.x < 17) {
    int zi = blockIdx.x * 256 + threadIdx.x;
    if (zi < 4100) counts[zi] = 0;  // counts[4096] + flags[4] contiguous
  }
  const int wv = threadIdx.x >> 6, lane = threadIdx.x & 63;
  const int row = blockIdx.x * 4 + wv;
  if (row >= NROWS + NCODES) return;
  const bool isA = row < NROWS;
  const int lrow = isA ? row : row - NROWS;
  const float* src = (isA ? z : cb) + (size_t)lrow * DIM;
  f32x4_t a = *(const f32x4_t*)(src + lane * 8);
  f32x4_t b = *(const f32x4_t*)(src + lane * 8 + 4);
  double s = 0.0;
#pragma unroll
  for (int e = 0; e < 4; ++e) s += (double)a[e] * a[e] + (double)b[e] * b[e];
#pragma unroll
  for (int off = 1; off < 64; off <<= 1) s += __shfl_xor(s, off);
  const float inv = (float)(1.0 / fmax(sqrt(s), 1e-8));
  union { unsigned short u[8]; uint4 v; } H;
#pragma unroll
  for (int e = 0; e < 4; ++e) {
    H.u[e] = f2bf(a[e] * inv);
    H.u[4 + e] = f2bf(b[e] * inv);
  }
  const int tb = lrow >> 7, r = lrow & 127;
  const int st = lane >> 3, u = lane & 7;
  unsigned char* chunk = (isA ? Aws : Bws) + ((size_t)tb * 8 + st) * 16384;
  *(uint4*)(chunk + r * 128 + ((u ^ (r & 7)) << 4)) = H.v;
}

// ---------------- pass-1 GEMM (hi*hi) + per-(row,group) top-8 ----------------
__global__ __launch_bounds__(256, 2) void gemm_p1_kernel(
    const unsigned char* __restrict__ Aws, const unsigned char* __restrict__ Bws,
    float2* __restrict__ top8) {
  __shared__ unsigned char lds[65536];
  float* slog = (float*)lds;

  const int tid = threadIdx.x;
  const int bid = blockIdx.x;
  const int xcd = bid & 7, q = bid >> 3;
  const int rb = xcd * 16 + (q >> 3), cg = q & 7;
  const int wave = tid >> 6, lane = tid & 63;
  const int wr = wave >> 1, wc = wave & 1;
  const int kg = lane >> 4, lr = lane & 15;

  float v8[8]; int id8[8];
#pragma unroll
  for (int s = 0; s < 8; ++s) { v8[s] = -3e38f; id8[s] = 0; }

  const unsigned char* Ach = Aws + (size_t)rb * 8 * 16384;

  for (int ct = 0; ct < 4; ++ct) {
    const int ctile = cg * 4 + ct;
    const int code0 = ctile * 128;
    const unsigned char* Bch = Bws + (size_t)ctile * 8 * 16384;

    f32x4_t acc[4][4];
#pragma unroll
    for (int m = 0; m < 4; ++m)
#pragma unroll
      for (int n = 0; n < 4; ++n) acc[m][n] = (f32x4_t){0.f, 0.f, 0.f, 0.f};

#pragma unroll
    for (int i = 0; i < 8; ++i) {
      const int j = wave * 8 + i;
      const unsigned char* sp = (j < 16) ? (Ach + (size_t)j * 1024 + lane * 16)
                                         : (Bch + (size_t)(j - 16) * 1024 + lane * 16);
      __builtin_amdgcn_global_load_lds(
          (const __attribute__((address_space(1))) void*)sp,
          (__attribute__((address_space(3))) void*)(lds + j * 1024), 16, 0, 0);
    }

    for (int st = 0; st < 8; ++st) {
      const int cur = st & 1;
      if (st < 7) {
        unsigned char* dbase = lds + (cur ^ 1) * 32768;
        const unsigned char* An = Ach + (size_t)(st + 1) * 16384;
        const unsigned char* Bn = Bch + (size_t)(st + 1) * 16384;
#pragma unroll
        for (int i = 0; i < 8; ++i) {
          const int j = wave * 8 + i;
          const unsigned char* sp = (j < 16) ? (An + (size_t)j * 1024 + lane * 16)
                                             : (Bn + (size_t)(j - 16) * 1024 + lane * 16);
          __builtin_amdgcn_global_load_lds(
              (const __attribute__((address_space(1))) void*)sp,
              (__attribute__((address_space(3))) void*)(dbase + j * 1024), 16, 0, 0);
        }
        asm volatile("s_waitcnt vmcnt(8)" ::: "memory");
      } else {
        asm volatile("s_waitcnt vmcnt(0)" ::: "memory");
      }
      __builtin_amdgcn_s_barrier();

      const unsigned char* base = lds + cur * 32768;
      bf16x8_t ah[2][4], bh[2][4];
#pragma unroll
      for (int k2 = 0; k2 < 2; ++k2) {
        const int u = k2 * 4 + kg;
#pragma unroll
        for (int m = 0; m < 4; ++m) {
          const int r = wr * 64 + m * 16 + lr;
          ah[k2][m] = *(const bf16x8_t*)(base + r * 128 + ((u ^ (r & 7)) << 4));
        }
#pragma unroll
        for (int n = 0; n < 4; ++n) {
          const int r = wc * 64 + n * 16 + lr;
          bh[k2][n] = *(const bf16x8_t*)(base + 16384 + r * 128 + ((u ^ (r & 7)) << 4));
        }
      }
#pragma unroll
      for (int k2 = 0; k2 < 2; ++k2)
#pragma unroll
        for (int m = 0; m < 4; ++m)
#pragma unroll
          for (int n = 0; n < 4; ++n)
            acc[m][n] = __builtin_amdgcn_mfma_f32_16x16x32_bf16(ah[k2][m], bh[k2][n], acc[m][n], 0, 0, 0);
      asm volatile("s_waitcnt lgkmcnt(0)" ::: "memory");
      __builtin_amdgcn_s_barrier();
    }
    __syncthreads();

#pragma unroll
    for (int ph = 0; ph < 2; ++ph) {
      if (wc == ph) {
#pragma unroll
        for (int m = 0; m < 4; ++m)
#pragma unroll
          for (int n = 0; n < 4; ++n)
#pragma unroll
            for (int j = 0; j < 4; ++j)
              slog[(wr * 64 + m * 16 + kg * 4 + j) * LSTR + n * 16 + lr] = acc[m][n][j];
      }
      __syncthreads();
      if (tid < 128) {
        const int gbase = code0 + ph * 64;
        for (int c = 0; c < 64; ++c) {
          float v = slog[tid * LSTR + c];
          if (v > v8[7]) {
            v8[7] = v; id8[7] = gbase + c;
#pragma unroll
            for (int s = 7; s > 0; --s)
              if (v8[s] > v8[s - 1]) {
                float tv = v8[s]; v8[s] = v8[s - 1]; v8[s - 1] = tv;
                int ti = id8[s]; id8[s] = id8[s - 1]; id8[s - 1] = ti;
              }
          }
        }
      }
      __syncthreads();
    }
  }

  if (tid < 128) {
    float2* p = top8 + ((size_t)(rb * 128 + tid) * 8 + cg) * 8;
#pragma unroll
    for (int s = 0; s < 8; ++s)
      p[s] = make_float2(v8[s], __builtin_bit_cast(float, id8[s]));
  }
}

// ---------------- resolve: mask probe + merge 8x top-8, classify rows ----------------
__global__ void resolve_kernel(const uint4* __restrict__ mk, const float2* __restrict__ top8,
                               int* __restrict__ idxf, int* __restrict__ cands,
                               int* __restrict__ full, unsigned* __restrict__ flags) {
  if (blockIdx.x == 0) {
    unsigned f = 0;
    for (int i = threadIdx.x; i < 1024; i += 256) {
      uint4 v = mk[i];
      f |= hz(v.x) | hz(v.y) | hz(v.z) | hz(v.w);
    }
    if (f) atomicOr(&flags[0], 1u);  // zero byte found -> int32 mask layout
  }
  const int row = blockIdx.x * 256 + threadIdx.x;
  if (row >= NROWS) return;
  const float2* e = top8 + (size_t)row * 64;
  float V1 = -3e38f; int I1 = 0;
  for (int j = 0; j < 64; ++j) {
    float v = e[j].x;
    if (v > V1) { V1 = v; I1 = __builtin_bit_cast(int, e[j].y); }
  }
  const float T = V1 - 2.0f * DELTA;
  bool fullscan = false;
#pragma unroll
  for (int g = 0; g < 8; ++g)
    if (e[g * 8 + 7].x >= T) fullscan = true;  // group top-8 may have truncated candidates
  int cnt = 0; int cid[MAXC];
  for (int j = 0; j < 64; ++j) {
    if (e[j].x >= T) { if (cnt < MAXC) cid[cnt] = __builtin_bit_cast(int, e[j].y); ++cnt; }
  }
  if (cnt > MAXC) fullscan = true;
  idxf[row] = I1;  // provably correct when cnt==1
  if (fullscan) {
    unsigned s = atomicAdd(&flags[2], 1u);
    if (s < NROWS) full[s] = row;
  } else if (cnt >= 2) {
    unsigned s = atomicAdd(&flags[1], 1u);
    int* o = cands + (size_t)s * 20;
    o[0] = row; o[1] = cnt;
#pragma unroll
    for (int c2 = 0; c2 < MAXC; ++c2) o[2 + c2] = (c2 < cnt) ? cid[c2] : 0;
  }
}

// ---------------- f64 candidate rescore: one wave per row ----------------
__global__ void rescore_cand_kernel(const float* __restrict__ z, const float* __restrict__ cb,
                                    const int* __restrict__ cands, const unsigned* __restrict__ flags,
                                    int* __restrict__ idxf) {
  const int lane = threadIdx.x & 63;
  const int gw = (blockIdx.x * 256 + threadIdx.x) >> 6;
  const unsigned n = flags[1];
  for (unsigned it = gw; it < n; it += 512) {
    const int* en = cands + (size_t)it * 20;
    const int row = en[0], cnt = en[1];
    const float* zr = z + (size_t)row * DIM + lane * 8;
    double zv[8];
#pragma unroll
    for (int j = 0; j < 8; ++j) zv[j] = (double)zr[j];
    double bs = -1e300; int bi = 1 << 30;
    for (int c = 0; c < cnt; ++c) {
      const int k = en[2 + c];
      const float* ck = cb + (size_t)k * DIM + lane * 8;
      double da = 0, nb = 0;
#pragma unroll
      for (int j = 0; j < 8; ++j) { double cv = ck[j]; da += zv[j] * cv; nb += cv * cv; }
#pragma unroll
      for (int off = 1; off < 64; off <<= 1) {
        da += __shfl_xor(da, off); nb += __shfl_xor(nb, off);
      }
      double sc = da / sqrt(nb);  // z-norm omitted: row-constant scale, argmax-invariant
      if (sc > bs || (sc == bs && k < bi)) { bs = sc; bi = k; }
    }
    if (lane == 0) idxf[row] = bi;
  }
}

// ---------------- f64 full-row referee: one BLOCK per row, ILP-4 per thread ----------------
__global__ void rescore_full_kernel(const float* __restrict__ z, const float* __restrict__ cb,
                                    const int* __restrict__ full, const unsigned* __restrict__ flags,
                                    int* __restrict__ idxf) {
  __shared__ float zrow[DIM];
  __shared__ double rv[256];
  __shared__ int ri[256];
  const int t = threadIdx.x;
  const unsigned n = flags[2];
  for (unsigned it = blockIdx.x; it < n; it += gridDim.x) {
    const int row = full[it];
    __syncthreads();
    for (int j = t; j < DIM; j += 256) zrow[j] = z[(size_t)row * DIM + j];
    __syncthreads();
    double best = -1e300; int bi = 1 << 30;
    for (int b = 0; b < 4; ++b) {
      const int k0 = t + b * 1024;  // codes k0, k0+256, k0+512, k0+768
      const float* c0 = cb + (size_t)(k0)       * DIM;
      const float* c1 = cb + (size_t)(k0 + 256) * DIM;
      const float* c2 = cb + (size_t)(k0 + 512) * DIM;
      const float* c3 = cb + (size_t)(k0 + 768) * DIM;
      double d0 = 0, d1 = 0, d2 = 0, d3 = 0, n0 = 0, n1 = 0, n2 = 0, n3 = 0;
      for (int j = 0; j < DIM; j += 4) {
        f32x4_t zq = *(const f32x4_t*)(zrow + j);
        f32x4_t a0 = *(const f32x4_t*)(c0 + j);
        f32x4_t a1 = *(const f32x4_t*)(c1 + j);
        f32x4_t a2 = *(const f32x4_t*)(c2 + j);
        f32x4_t a3 = *(const f32x4_t*)(c3 + j);
#pragma unroll
        for (int e = 0; e < 4; ++e) {
          const double zd = (double)zq[e];
          const double v0 = (double)a0[e], v1 = (double)a1[e];
          const double v2 = (double)a2[e], v3 = (double)a3[e];
          d0 += zd * v0; n0 += v0 * v0;
          d1 += zd * v1; n1 += v1 * v1;
          d2 += zd * v2; n2 += v2 * v2;
          d3 += zd * v3; n3 += v3 * v3;
        }
      }
      const double s0 = d0 / sqrt(n0), s1 = d1 / sqrt(n1);
      const double s2 = d2 / sqrt(n2), s3 = d3 / sqrt(n3);
      if (s0 > best || (s0 == best && k0       < bi)) { best = s0; bi = k0; }
      if (s1 > best || (s1 == best && k0 + 256 < bi)) { best = s1; bi = k0 + 256; }
      if (s2 > best || (s2 == best && k0 + 512 < bi)) { best = s2; bi = k0 + 512; }
      if (s3 > best || (s3 == best && k0 + 768 < bi)) { best = s3; bi = k0 + 768; }
    }
    rv[t] = best; ri[t] = bi; __syncthreads();
    for (int off = 128; off; off >>= 1) {
      if (t < off) {
        if (rv[t + off] > rv[t] || (rv[t + off] == rv[t] && ri[t + off] < ri[t])) {
          rv[t] = rv[t + off]; ri[t] = ri[t + off];
        }
      }
      __syncthreads();
    }
    if (t == 0) idxf[row] = ri[0];
  }
}

// ---------------- gather + straight-through + partial losses ----------------
__global__ void outputs_kernel(const float* __restrict__ z, const float* __restrict__ cb,
                               const unsigned char* __restrict__ mask8, const int* __restrict__ mask32,
                               const unsigned* __restrict__ flags, const int* __restrict__ idxf,
                               float* __restrict__ out, unsigned* __restrict__ counts,
                               double* __restrict__ cpart) {
  __shared__ double wsum[4];
  const int wv = threadIdx.x >> 6, lane = threadIdx.x & 63;
  const int row = blockIdx.x * 4 + wv;
  int idx = idxf[row];
  idx = (idx < 0) ? 0 : ((idx > NCODES - 1) ? NCODES - 1 : idx);  // defensive clamp
  const int mi = flags[0] ? (mask32[row] != 0) : (mask8[row] != 0);
  const float mf = mi ? 1.0f : 0.0f;
  const float* zr = z + (size_t)row * DIM;
  const float* cr = cb + (size_t)idx * DIM;
  double cs = 0.0;
#pragma unroll
  for (int h = 0; h < 2; ++h) {
    const int j = h * 256 + lane * 4;
    f32x4_t c  = *(const f32x4_t*)(cr + j);
    f32x4_t ze = *(const f32x4_t*)(zr + j);
    f32x4_t zq, zs;
#pragma unroll
    for (int e = 0; e < 4; ++e) {
      float qv = c[e] * mf;
      float d = qv - ze[e];
      zq[e] = qv;
      zs[e] = ze[e] + d;
      cs += (double)(d * d) * mf;
    }
    *(f32x4_t*)(out + OUT_ZQ   + (size_t)row * DIM + j) = zq;
    *(f32x4_t*)(out + OUT_ZQST + (size_t)row * DIM + j) = zs;
  }
#pragma unroll
  for (int off = 32; off; off >>= 1) cs += __shfl_down(cs, off);
  if (lane == 0) {
    wsum[wv] = cs;
    out[OUT_IDX + row] = (float)idx;
    if (mi) atomicAdd(&counts[idx], 1u);
  }
  __syncthreads();
  if (threadIdx.x == 0) cpart[blockIdx.x] = wsum[0] + wsum[1] + wsum[2] + wsum[3];
}

// ---------------- scalars ----------------
__global__ void finalize_kernel(const double* __restrict__ cpart, const unsigned* __restrict__ counts,
                                float* __restrict__ out) {
  __shared__ double sd[256];
  const int t = threadIdx.x;
  double s = 0;
  for (int i = t; i < 4096; i += 256) s += cpart[i];
  sd[t] = s; __syncthreads();
  for (int off = 128; off; off >>= 1) { if (t < off) sd[t] += sd[t + off]; __syncthreads(); }
  const double commit_sum = sd[0];
  __syncthreads();
  double c = 0;
  for (int i = t; i < 4096; i += 256) c += (double)counts[i];
  sd[t] = c; __syncthreads();
  for (int off = 128; off; off >>= 1) { if (t < off) sd[t] += sd[t + off]; __syncthreads(); }
  const double totc = sd[0];
  __syncthreads();
  const double denom = totc + 1e-5;
  double ent = 0;
  for (int i = t; i < 4096; i += 256) {
    double p = (double)counts[i] / denom;
    ent -= p * log(p + 1e-5);
  }
  sd[t] = ent; __syncthreads();
  for (int off = 128; off; off >>= 1) { if (t < off) sd[t] += sd[t + off]; __syncthreads(); }
  if (t == 0) {
    const double valid = fmax(totc, 1.0);
    const double commitment = commit_sum / valid;
    out[OUT_VQ]     = (float)(0.25 * commitment);
    out[OUT_COMMIT] = (float)commitment;
    out[OUT_PERP]   = (float)exp(sd[0]);
  }
}

extern "C" void kernel_launch(void* const* d_in, const int* in_sizes, int n_in,
                              void* d_out, int out_size, void* d_ws, size_t ws_size,
                              hipStream_t stream) {
  const float* z  = (const float*)d_in[0];
  const void*  mk = d_in[1];
  const float* cb = (const float*)d_in[2];
  float* out = (float*)d_out;
  char* ws = (char*)d_ws;

  unsigned char* Aws    = (unsigned char*)(ws + WS_A);
  unsigned char* Bws    = (unsigned char*)(ws + WS_B);
  float2*        top8   = (float2*)(ws + WS_TOP8);
  unsigned*      counts = (unsigned*)(ws + WS_COUNTS);
  unsigned*      flags  = (unsigned*)(ws + WS_FLAGS);
  int*           idxf   = (int*)(ws + WS_IDX);
  int*           cands  = (int*)(ws + WS_CANDS);
  int*           full   = (int*)(ws + WS_FULL);
  double*        cpart  = (double*)(ws + WS_CPART);

  prep_kernel<<<(NROWS + NCODES) / 4, 256, 0, stream>>>(z, cb, Aws, Bws, counts);
  gemm_p1_kernel<<<1024, 256, 0, stream>>>(Aws, Bws, top8);
  resolve_kernel<<<NROWS / 256, 256, 0, stream>>>((const uint4*)mk, top8, idxf, cands, full, flags);
  rescore_cand_kernel<<<128, 256, 0, stream>>>(z, cb, cands, flags, idxf);
  rescore_full_kernel<<<256, 256, 0, stream>>>(z, cb, full, flags, idxf);
  outputs_kernel<<<NROWS / 4, 256, 0, stream>>>(z, cb, (const unsigned char*)mk, (const int*)mk,
                                                flags, idxf, out, counts, cpart);
  finalize_kernel<<<1, 256, 0, stream>>>(cpart, counts, out);
}